// Round 5
// baseline (556.144 us; speedup 1.0000x reference)
//
#include <hip/hip_runtime.h>
#include <hip/hip_bf16.h>

#define NODES 4097
#define TT 4096
#define CIN 64
#define HID 128
#define BATCH 64
#define EPS 1e-5f

typedef short bf16x8 __attribute__((ext_vector_type(8)));   // 8 bf16 = 4 VGPRs
typedef float f32x16 __attribute__((ext_vector_type(16)));  // 32x32 acc

// async global->LDS DMA, 16 B per lane; LDS dst = wave-uniform base + lane*16
__device__ __forceinline__ void load_lds16(const void* g, void* l) {
    __builtin_amdgcn_global_load_lds(
        (const __attribute__((address_space(1))) unsigned int*)(uintptr_t)g,
        (__attribute__((address_space(3))) unsigned int*)(uintptr_t)l,
        16, 0, 0);
}

// ---------------- transpose feats (B,C,N) fp32 -> fT (B,N,C) bf16, both encoders ----------------
__global__ __launch_bounds__(256) void k_transpose(const float* __restrict__ f0,
                                                   const float* __restrict__ f1,
                                                   __hip_bfloat16* __restrict__ out) {
    __shared__ float tile[32][33];
    int z = blockIdx.z;
    int enc = z >> 6, b = z & 63;
    const float* in = enc ? f1 : f0;
    __hip_bfloat16* o = out + (size_t)enc * BATCH * NODES * CIN;
    int n0 = blockIdx.x * 32;
    int c0 = blockIdx.y * 32;
    int tx = threadIdx.x, ty = threadIdx.y;  // (32,8)
    for (int i = 0; i < 32; i += 8) {
        int n = n0 + tx, c = c0 + ty + i;
        float v = 0.f;
        if (n < NODES) v = in[((size_t)b * CIN + c) * NODES + n];
        tile[ty + i][tx] = v;
    }
    __syncthreads();
    for (int i = 0; i < 32; i += 8) {
        int n = n0 + ty + i, c = c0 + tx;
        if (n < NODES) o[((size_t)b * NODES + n) * CIN + c] = __float2bfloat16(tile[tx][ty + i]);
    }
}

// ---------------- W (HID,C,3) fp32 -> frag-major bf16 B-operand layout, both encoders ----------------
// Wp id = (ks*4 + ct)*64 + lane holds 8 bf16: B[k=ks*16+(lane>>5)*8+j][n=ct*32+(lane&31)]
// k = slot*C + c; B[k][n] = W[(n*C + c)*3 + slot]
__global__ void k_wprep(const float* __restrict__ W0, const float* __restrict__ W1,
                        __hip_bfloat16* __restrict__ Wp, int C) {
    int enc = blockIdx.y;
    const float* W = enc ? W1 : W0;
    __hip_bfloat16* o = Wp + (size_t)enc * 3 * C * HID;
    int id = blockIdx.x * 256 + threadIdx.x;
    int total = 3 * C * HID / 8;
    if (id >= total) return;
    int lane = id & 63;
    int ct = (id >> 6) & 3;
    int ks = id >> 8;
    int n = ct * 32 + (lane & 31);
    int kb = ks * 16 + (lane >> 5) * 8;
    union { int4 i; __hip_bfloat16 h[8]; } u;
#pragma unroll
    for (int j = 0; j < 8; ++j) {
        int k = kb + j;
        int slot = k / C, c = k % C;
        u.h[j] = __float2bfloat16(W[(n * C + c) * 3 + slot]);
    }
    ((int4*)o)[id] = u.i;
}

// ---------------- gather-conv via MFMA: B in LDS, A prefetched to registers ----------------
// R0 structure, smaller phases: grid 4096 XCD-swizzled (xcd=L&7, node-tile fastest,
// b=xcd+8*bg pinned per XCD). Block = 4 waves, tile 128 nodes x 128 o.
// PK=6 ksteps/phase: stage 24 KB frag-major Wp via contiguous global_load_lds, prefetch
// the phase's 6 A-frags (per-lane 16B gathers) into registers BEFORE the barrier
// (latency hides under the B drain); MFMA loop reads B via ds_read_b128, zero globals.
// Occupancy: 24 KB LDS + __launch_bounds__(256,4) -> target 4 blocks/CU (16 waves/CU,
// vs R0's 12). Reg demand ~= 64 AGPR acc + ~50 VGPR (areg[6] only) < 128 cap.
// R2 lesson: min-waves=6 (85-reg cap) spills the accumulator -> never exceed 4 here.
template <int C, bool POOL>
__global__ __launch_bounds__(256, 4) void k_conv_mfma(
    const __hip_bfloat16* __restrict__ xT,    // [2][B][N][C]
    const int* __restrict__ children,
    const __hip_bfloat16* __restrict__ Wp,    // [2][3C*HID] frag-major
    const float* __restrict__ bias0, const float* __restrict__ bias1,
    __hip_bfloat16* __restrict__ y,           // [2][B][N][HID] raw out (if !POOL)
    float* __restrict__ sums,                 // [2B][2] this layer's sum/sumsq
    float* __restrict__ pool_part) {          // [2B][32][HID] (if POOL)
    constexpr int KSc = C / 16;             // ksteps per child-slot (4 or 8)
    constexpr int KS = 3 * KSc;             // 12 or 24 ksteps total
    constexpr int PK = 6;                   // ksteps per phase (24 KB LDS)
    constexpr int PH = KS / PK;             // 2 or 4 phases
    // ---- XCD-aware swizzle ----
    int L = blockIdx.x;
    int xcd = L & 7;
    int idx = L >> 3;
    int xt = idx & 31;              // node-tile (fastest within XCD)
    int bg = (idx >> 5) & 7;
    int enc = idx >> 8;
    int b = xcd + 8 * bg;           // b pinned to one XCD -> gather set stays in L2
    const int t0 = xt * 128;
    const int tid = threadIdx.x;
    const int lane = tid & 63;
    const int w = tid >> 6;
    const int hi = lane >> 5;

    __shared__ __align__(16) int4 B_lds[PK * 4 * 64];  // 24 KB, chunk c = (kk*4+cti)

    const __hip_bfloat16* x = xT + (size_t)enc * BATCH * NODES * C;
    const int4* WpB = (const int4*)(Wp + (size_t)enc * 3 * C * HID);
    const float* bias = enc ? bias1 : bias0;
    const int sb = enc * BATCH + b;
    const size_t rowbase = (size_t)b * NODES;
    const long cb3 = (long)b * (3 * TT);
    const int tnode = t0 + w * 32 + (lane & 31);  // node this lane's A-frags cover

    // gathered-row pointers, offset by this lane's k-octet half
    const int4* ap[3];
#pragma unroll
    for (int s = 0; s < 3; ++s) {
        int child = children[cb3 + (long)tnode * 3 + s];
        ap[s] = (const int4*)(x + (rowbase + child) * C) + hi;
    }

    f32x16 acc[4] = {};
#pragma unroll
    for (int ph = 0; ph < PH; ++ph) {
        if (ph) __syncthreads();  // prior phase's ds_reads done before overwrite
        // ---- stage this phase's B (24 KB, contiguous, coalesced) ----
#pragma unroll
        for (int i = 0; i < PK; ++i) {
            int chunk = w * PK + i;
            load_lds16(WpB + (size_t)(ph * PK * 4 + chunk) * 64 + lane, B_lds + chunk * 64);
        }
        // ---- prefetch this phase's A-frags into registers (hide under B drain) ----
        int4 areg[PK];
#pragma unroll
        for (int kk = 0; kk < PK; ++kk) {
            int ksg = ph * PK + kk;
            areg[kk] = ap[ksg / KSc][(ksg % KSc) * 2];
        }
        __syncthreads();  // drains DMA + A-gathers (vmcnt 0) + barrier
        // ---- MFMA loop: zero global loads ----
#pragma unroll
        for (int kk = 0; kk < PK; ++kk) {
            union { int4 i; bf16x8 v; } a;
            a.i = areg[kk];
#pragma unroll
            for (int cti = 0; cti < 4; ++cti) {
                union { int4 i; bf16x8 v; } bb;
                bb.i = B_lds[(kk * 4 + cti) * 64 + lane];
                acc[cti] = __builtin_amdgcn_mfma_f32_32x32x16_bf16(a.v, bb.v, acc[cti], 0, 0, 0);
            }
        }
    }

    // ---- epilogue: bias, sums, pool-max / y-write ----
    if (POOL) __syncthreads();  // all waves done reading B_lds before pm overlay
    float* pm = (float*)B_lds;  // [8*128] pool partial maxima (POOL only)
    float bsum = 0.f, bss = 0.f;
    __hip_bfloat16* yp = POOL ? nullptr : (y + (size_t)enc * BATCH * NODES * HID);
    const int rbase = t0 + w * 32 + 4 * hi + 1;  // +1: node-0 shift
#pragma unroll
    for (int cti = 0; cti < 4; ++cti) {
        int o = cti * 32 + (lane & 31);
        float bv = bias[o];
        f32x16 a2 = acc[cti];
        float lmax = -3.4e38f;
#pragma unroll
        for (int reg = 0; reg < 16; ++reg) {
            float v = a2[reg] + bv;
            bsum += v;
            bss += v * v;
            if (POOL) {
                lmax = fmaxf(lmax, v);
            } else {
                int row = rbase + (reg & 3) + 8 * (reg >> 2);
                yp[(rowbase + row) * HID + o] = __float2bfloat16(v);
            }
        }
        if (POOL) pm[(w * 2 + hi) * 128 + o] = lmax;  // o consecutive per lane: no conflicts
    }
    if (!POOL && xt == 0 && tid < HID)
        yp[rowbase * HID + tid] = __float2bfloat16(0.f);

    // ---- wave-level sum/sumsq reduction: 6 shfl steps, no barriers ----
#pragma unroll
    for (int m2 = 1; m2 < 64; m2 <<= 1) {
        bsum += __shfl_xor(bsum, m2, 64);
        bss += __shfl_xor(bss, m2, 64);
    }
    if (lane == 0) {
        atomicAdd(&sums[sb * 2], bsum);
        atomicAdd(&sums[sb * 2 + 1], bss);
    }
    if (POOL) {
        __syncthreads();  // pm complete across waves
        if (tid < HID) {
            float m = -3.4e38f;
#pragma unroll
            for (int s2 = 0; s2 < 8; ++s2) m = fmaxf(m, pm[s2 * 128 + tid]);
            pool_part[((size_t)sb * 32 + xt) * HID + tid] = m;
        }
    }
}

// ---------------- in-place norm+relu of y1 (bf16 x8 vectorized); stats from sums ----------------
__global__ __launch_bounds__(256) void k_norm(__hip_bfloat16* __restrict__ y,
                                              const float* __restrict__ sums) {
    constexpr int Q = NODES * HID / 8;  // 65552 int4s per (enc,b) slice
    int s = blockIdx.y;                 // enc*64 + b
    int q = blockIdx.x * 256 + threadIdx.x;
    if (q >= Q) return;
    const float M = (float)HID * (float)NODES;
    float S = sums[s * 2], SS = sums[s * 2 + 1];
    float mean = S / M;
    float var = (SS - S * S / M) / (M - 1.f);
    float scale = 1.f / (sqrtf(fmaxf(var, 0.f)) + EPS);
    int4* p = (int4*)(y + (size_t)s * NODES * HID) + q;
    union { int4 i; __hip_bfloat16 h[8]; } u;
    u.i = *p;
#pragma unroll
    for (int j = 0; j < 8; ++j) {
        float f = (__bfloat162float(u.h[j]) - mean) * scale;
        u.h[j] = __float2bfloat16(f > 0.f ? f : 0.f);
    }
    *p = u.i;
}

// ---------------- finalize: stats2 + pool reduce + norm/relu + FC (mu/logvar) ----------------
__global__ __launch_bounds__(128) void k_fin(const float* __restrict__ part,
                                             const float* __restrict__ sums2,
                                             const float* __restrict__ Wmu, const float* __restrict__ bmu,
                                             const float* __restrict__ Wlv, const float* __restrict__ blv,
                                             float* __restrict__ out) {
    int b = blockIdx.x, tid = threadIdx.x;
    __shared__ float cb[256];
    const float M = (float)HID * (float)NODES;
#pragma unroll
    for (int enc = 0; enc < 2; ++enc) {
        int sb = enc * BATCH + b;
        float S = sums2[sb * 2], SS = sums2[sb * 2 + 1];
        float mean = S / M;
        float var = (SS - S * S / M) / (M - 1.f);
        float scale = 1.f / (sqrtf(fmaxf(var, 0.f)) + EPS);
        float m = 0.f;  // node-0 raw value is 0
#pragma unroll 4
        for (int s = 0; s < 32; ++s)
            m = fmaxf(m, part[((size_t)sb * 32 + s) * HID + tid]);
        float v = (m - mean) * scale;  // monotone: max then transform
        cb[enc * 128 + tid] = v > 0.f ? v : 0.f;
    }
    __syncthreads();
    const float* W = (tid < 64) ? Wmu : Wlv;
    int l = tid & 63;
    float s = (tid < 64) ? bmu[l] : blv[l];
    for (int j = 0; j < 256; ++j) s += cb[j] * W[l * 256 + j];
    out[(tid < 64 ? 0 : BATCH * 64) + b * 64 + l] = s;
}

extern "C" void kernel_launch(void* const* d_in, const int* in_sizes, int n_in,
                              void* d_out, int out_size, void* d_ws, size_t ws_size,
                              hipStream_t stream) {
    const int* children = (const int*)d_in[2];
    const float* Wmu = (const float*)d_in[11];
    const float* bmu = (const float*)d_in[12];
    const float* Wlv = (const float*)d_in[13];
    const float* blv = (const float*)d_in[14];

    // ---- workspace layout (256B aligned) ----
    char* ws = (char*)d_ws;
    size_t off = 0;
    auto alloc = [&](size_t bytes) { void* p = ws + off; off += (bytes + 255) & ~(size_t)255; return p; };
    float* sums = (float*)alloc(2 * 2 * BATCH * 2 * sizeof(float));  // [layer][enc*B+b][2]
    float* pool_part = (float*)alloc((size_t)2 * BATCH * 32 * HID * sizeof(float));
    __hip_bfloat16* Wp1 = (__hip_bfloat16*)alloc((size_t)2 * 3 * CIN * HID * sizeof(__hip_bfloat16));
    __hip_bfloat16* Wp2 = (__hip_bfloat16*)alloc((size_t)2 * 3 * HID * HID * sizeof(__hip_bfloat16));
    __hip_bfloat16* fT = (__hip_bfloat16*)alloc((size_t)2 * BATCH * NODES * CIN * sizeof(__hip_bfloat16));
    __hip_bfloat16* y1 = (__hip_bfloat16*)alloc((size_t)2 * BATCH * NODES * HID * sizeof(__hip_bfloat16));

    hipMemsetAsync(sums, 0, 2 * 2 * BATCH * 2 * sizeof(float), stream);

    k_wprep<<<dim3(3 * CIN * HID / 8 / 256, 2), 256, 0, stream>>>(
        (const float*)d_in[3], (const float*)d_in[7], Wp1, CIN);
    k_wprep<<<dim3(3 * HID * HID / 8 / 256, 2), 256, 0, stream>>>(
        (const float*)d_in[5], (const float*)d_in[9], Wp2, HID);
    k_transpose<<<dim3(129, 2, 2 * BATCH), dim3(32, 8), 0, stream>>>(
        (const float*)d_in[0], (const float*)d_in[1], fT);

    // layer 1: raw conv out -> y1, stats accumulated via per-wave atomics
    k_conv_mfma<CIN, false><<<4096, 256, 0, stream>>>(
        fT, children, Wp1, (const float*)d_in[4], (const float*)d_in[8],
        y1, sums, nullptr);
    // norm+relu y1 in place (stats computed inline from sums)
    k_norm<<<dim3((NODES * HID / 8 + 255) / 256, 2 * BATCH), 256, 0, stream>>>(y1, sums);
    // layer 2: plain gather of normalized y1
    k_conv_mfma<HID, true><<<4096, 256, 0, stream>>>(
        y1, children, Wp2, (const float*)d_in[6], (const float*)d_in[10],
        nullptr, sums + 256, pool_part);
    // stats2 + pool reduce + norm/relu + FC in one small kernel
    k_fin<<<BATCH, 128, 0, stream>>>(pool_part, sums + 256, Wmu, bmu, Wlv, blv, (float*)d_out);
}

// Round 7
// 525.712 us; speedup vs baseline: 1.0579x; 1.0579x over previous
//
#include <hip/hip_runtime.h>
#include <hip/hip_bf16.h>

#define NODES 4097
#define TT 4096
#define CIN 64
#define HID 128
#define BATCH 64
#define EPS 1e-5f

typedef short bf16x8 __attribute__((ext_vector_type(8)));   // 8 bf16 = 4 VGPRs
typedef float f32x16 __attribute__((ext_vector_type(16)));  // 32x32 acc

// async global->LDS DMA, 16 B per lane; LDS dst = wave-uniform base + lane*16
__device__ __forceinline__ void load_lds16(const void* g, void* l) {
    __builtin_amdgcn_global_load_lds(
        (const __attribute__((address_space(1))) unsigned int*)(uintptr_t)g,
        (__attribute__((address_space(3))) unsigned int*)(uintptr_t)l,
        16, 0, 0);
}

// ---------------- transpose feats (B,C,N) fp32 -> fT (B,N,C) bf16, both encoders ----------------
__global__ __launch_bounds__(256) void k_transpose(const float* __restrict__ f0,
                                                   const float* __restrict__ f1,
                                                   __hip_bfloat16* __restrict__ out) {
    __shared__ float tile[32][33];
    int z = blockIdx.z;
    int enc = z >> 6, b = z & 63;
    const float* in = enc ? f1 : f0;
    __hip_bfloat16* o = out + (size_t)enc * BATCH * NODES * CIN;
    int n0 = blockIdx.x * 32;
    int c0 = blockIdx.y * 32;
    int tx = threadIdx.x, ty = threadIdx.y;  // (32,8)
    for (int i = 0; i < 32; i += 8) {
        int n = n0 + tx, c = c0 + ty + i;
        float v = 0.f;
        if (n < NODES) v = in[((size_t)b * CIN + c) * NODES + n];
        tile[ty + i][tx] = v;
    }
    __syncthreads();
    for (int i = 0; i < 32; i += 8) {
        int n = n0 + ty + i, c = c0 + tx;
        if (n < NODES) o[((size_t)b * NODES + n) * CIN + c] = __float2bfloat16(tile[tx][ty + i]);
    }
}

// ---------------- W (HID,C,3) fp32 -> frag-major bf16 B-operand layout, both encoders ----------------
// Wp id = (ks*4 + ct)*64 + lane holds 8 bf16: B[k=ks*16+(lane>>5)*8+j][n=ct*32+(lane&31)]
// k = slot*C + c; B[k][n] = W[(n*C + c)*3 + slot]
__global__ void k_wprep(const float* __restrict__ W0, const float* __restrict__ W1,
                        __hip_bfloat16* __restrict__ Wp, int C) {
    int enc = blockIdx.y;
    const float* W = enc ? W1 : W0;
    __hip_bfloat16* o = Wp + (size_t)enc * 3 * C * HID;
    int id = blockIdx.x * 256 + threadIdx.x;
    int total = 3 * C * HID / 8;
    if (id >= total) return;
    int lane = id & 63;
    int ct = (id >> 6) & 3;
    int ks = id >> 8;
    int n = ct * 32 + (lane & 31);
    int kb = ks * 16 + (lane >> 5) * 8;
    union { int4 i; __hip_bfloat16 h[8]; } u;
#pragma unroll
    for (int j = 0; j < 8; ++j) {
        int k = kb + j;
        int slot = k / C, c = k % C;
        u.h[j] = __float2bfloat16(W[(n * C + c) * 3 + slot]);
    }
    ((int4*)o)[id] = u.i;
}

// ---------------- gather-conv via MFMA: pipelined double-buffered B staging ----------------
// Grid 4096 XCD-swizzled (xcd=L&7, node-tile fastest, b=xcd+8*bg pinned per XCD).
// Block = 4 waves, tile 128 nodes x 128 o. PK=6 ksteps/phase, LDS dbuf 2x24 KB.
// T3+T4 schedule (2 barriers/phase, NO vmcnt(0) drains in steady state):
//   phase p: issue DMA(p+1 -> other buf) + gather A(p+1) into spare aregs, then
//   `s_waitcnt vmcnt(12)` (12 just-issued ops stay IN FLIGHT; phase p's 12 are
//   retired), s_barrier, 24 MFMAs on buf[p&1], s_barrier.
// sched_barrier(0) fences pin the order (rule #18: hipcc hoists reg-only/LDS ops
// past inline-asm waits and raw barriers otherwise).
// R0/R5 lesson: wall time was linear in vmcnt(0)-drain count (~40 us/phase).
// R2 lesson: no __launch_bounds__ min-waves (acc spills to scratch).
// VMEM discipline: bias/children loads hoisted above the loop; loop body issues
// exactly 12 VMEM ops per phase so the vmcnt immediate is exact.
template <int C, bool POOL>
__global__ __launch_bounds__(256) void k_conv_mfma(
    const __hip_bfloat16* __restrict__ xT,    // [2][B][N][C]
    const int* __restrict__ children,
    const __hip_bfloat16* __restrict__ Wp,    // [2][3C*HID] frag-major
    const float* __restrict__ bias0, const float* __restrict__ bias1,
    __hip_bfloat16* __restrict__ y,           // [2][B][N][HID] raw out (if !POOL)
    float* __restrict__ sums,                 // [2B][2] this layer's sum/sumsq
    float* __restrict__ pool_part) {          // [2B][32][HID] (if POOL)
    constexpr int KSc = C / 16;             // ksteps per child-slot (4 or 8)
    constexpr int KS = 3 * KSc;             // 12 or 24 ksteps total
    constexpr int PK = 6;                   // ksteps per phase (24 KB per buffer)
    constexpr int PH = KS / PK;             // 2 or 4 phases
    // ---- XCD-aware swizzle ----
    int L = blockIdx.x;
    int xcd = L & 7;
    int idx = L >> 3;
    int xt = idx & 31;              // node-tile (fastest within XCD)
    int bg = (idx >> 5) & 7;
    int enc = idx >> 8;
    int b = xcd + 8 * bg;           // b pinned to one XCD -> gather set stays in L2
    const int t0 = xt * 128;
    const int tid = threadIdx.x;
    const int lane = tid & 63;
    const int w = tid >> 6;
    const int hi = lane >> 5;

    __shared__ __align__(16) int4 B_lds[2][PK * 4 * 64];  // 2 x 24 KB
    __shared__ float pm[8 * 128];                         // pool partial maxima (4 KB)

    const __hip_bfloat16* x = xT + (size_t)enc * BATCH * NODES * C;
    const int4* WpB = (const int4*)(Wp + (size_t)enc * 3 * C * HID);
    const float* bias = enc ? bias1 : bias0;
    const int sb = enc * BATCH + b;
    const size_t rowbase = (size_t)b * NODES;
    const long cb3 = (long)b * (3 * TT);
    const int tnode = t0 + w * 32 + (lane & 31);  // node this lane's A-frags cover

    // ---- hoist ALL loop-invariant VMEM above the pipeline (exact vmcnt counting) ----
    float bv4[4];
#pragma unroll
    for (int cti = 0; cti < 4; ++cti) bv4[cti] = bias[cti * 32 + (lane & 31)];
    const int4* ap[3];
#pragma unroll
    for (int s = 0; s < 3; ++s) {
        int child = children[cb3 + (long)tnode * 3 + s];
        ap[s] = (const int4*)(x + (rowbase + child) * C) + hi;
    }

    // ---- pipeline helpers (inlined; all register indices static after unroll) ----
    auto STAGE = [&](int ph, int buf) {
#pragma unroll
        for (int i = 0; i < PK; ++i) {
            int c = w * PK + i;
            load_lds16(WpB + (size_t)(ph * PK * 4 + c) * 64 + lane, &B_lds[buf][c * 64]);
        }
    };
    auto GATHER = [&](int ph, int4* ar) {
#pragma unroll
        for (int kk = 0; kk < PK; ++kk) {
            int ksg = ph * PK + kk;
            ar[kk] = ap[ksg / KSc][(ksg % KSc) * 2];
        }
    };

    f32x16 acc[4] = {};
    int4 aregA[PK], aregB[PK];

    STAGE(0, 0);
    GATHER(0, aregA);
#pragma unroll
    for (int ph = 0; ph < PH; ++ph) {
        const int cur = ph & 1;
        if (ph + 1 < PH) {
            STAGE(ph + 1, cur ^ 1);                    // next phase's B -> other buffer
            GATHER(ph + 1, (ph & 1) ? aregA : aregB);  // next phase's A -> spare regs
            __builtin_amdgcn_sched_barrier(0);         // pin: all 12 issued before the wait
            asm volatile("s_waitcnt vmcnt(12)" ::: "memory");  // phase ph's 12 retired; 12 in flight
        } else {
            __builtin_amdgcn_sched_barrier(0);
            asm volatile("s_waitcnt vmcnt(0)" ::: "memory");   // final phase: full drain
        }
        __builtin_amdgcn_sched_barrier(0);             // nothing crosses the wait
        __builtin_amdgcn_s_barrier();                  // buf[cur] complete across all waves
        __builtin_amdgcn_sched_barrier(0);             // ds_reads below stay below the barrier
        const int4* ar = (ph & 1) ? aregB : aregA;
#pragma unroll
        for (int kk = 0; kk < PK; ++kk) {
            union { int4 i; bf16x8 v; } a;
            a.i = ar[kk];
#pragma unroll
            for (int cti = 0; cti < 4; ++cti) {
                union { int4 i; bf16x8 v; } bb;
                bb.i = B_lds[cur][(kk * 4 + cti) * 64 + lane];
                acc[cti] = __builtin_amdgcn_mfma_f32_32x32x16_bf16(a.v, bb.v, acc[cti], 0, 0, 0);
            }
        }
        __builtin_amdgcn_sched_barrier(0);             // all reads of buf[cur] precede barrier
        __builtin_amdgcn_s_barrier();                  // readers done before buf[cur] restaged
        __builtin_amdgcn_sched_barrier(0);             // next STAGE stays after barrier
    }

    // ---- epilogue: bias, sums, pool-max / y-write ----
    float bsum = 0.f, bss = 0.f;
    __hip_bfloat16* yp = POOL ? nullptr : (y + (size_t)enc * BATCH * NODES * HID);
    const int rbase = t0 + w * 32 + 4 * hi + 1;  // +1: node-0 shift
#pragma unroll
    for (int cti = 0; cti < 4; ++cti) {
        int o = cti * 32 + (lane & 31);
        float bv = bv4[cti];
        f32x16 a2 = acc[cti];
        float lmax = -3.4e38f;
#pragma unroll
        for (int reg = 0; reg < 16; ++reg) {
            float v = a2[reg] + bv;
            bsum += v;
            bss += v * v;
            if (POOL) {
                lmax = fmaxf(lmax, v);
            } else {
                int row = rbase + (reg & 3) + 8 * (reg >> 2);
                yp[(rowbase + row) * HID + o] = __float2bfloat16(v);
            }
        }
        if (POOL) pm[(w * 2 + hi) * 128 + o] = lmax;  // o consecutive per lane: no conflicts
    }
    if (!POOL && xt == 0 && tid < HID)
        yp[rowbase * HID + tid] = __float2bfloat16(0.f);

    // ---- wave-level sum/sumsq reduction: 6 shfl steps, no barriers ----
#pragma unroll
    for (int m2 = 1; m2 < 64; m2 <<= 1) {
        bsum += __shfl_xor(bsum, m2, 64);
        bss += __shfl_xor(bss, m2, 64);
    }
    if (lane == 0) {
        atomicAdd(&sums[sb * 2], bsum);
        atomicAdd(&sums[sb * 2 + 1], bss);
    }
    if (POOL) {
        __syncthreads();  // pm complete across waves
        if (tid < HID) {
            float m = -3.4e38f;
#pragma unroll
            for (int s2 = 0; s2 < 8; ++s2) m = fmaxf(m, pm[s2 * 128 + tid]);
            pool_part[((size_t)sb * 32 + xt) * HID + tid] = m;
        }
    }
}

// ---------------- in-place norm+relu of y1 (bf16 x8 vectorized); stats from sums ----------------
__global__ __launch_bounds__(256) void k_norm(__hip_bfloat16* __restrict__ y,
                                              const float* __restrict__ sums) {
    constexpr int Q = NODES * HID / 8;  // 65552 int4s per (enc,b) slice
    int s = blockIdx.y;                 // enc*64 + b
    int q = blockIdx.x * 256 + threadIdx.x;
    if (q >= Q) return;
    const float M = (float)HID * (float)NODES;
    float S = sums[s * 2], SS = sums[s * 2 + 1];
    float mean = S / M;
    float var = (SS - S * S / M) / (M - 1.f);
    float scale = 1.f / (sqrtf(fmaxf(var, 0.f)) + EPS);
    int4* p = (int4*)(y + (size_t)s * NODES * HID) + q;
    union { int4 i; __hip_bfloat16 h[8]; } u;
    u.i = *p;
#pragma unroll
    for (int j = 0; j < 8; ++j) {
        float f = (__bfloat162float(u.h[j]) - mean) * scale;
        u.h[j] = __float2bfloat16(f > 0.f ? f : 0.f);
    }
    *p = u.i;
}

// ---------------- finalize: stats2 + pool reduce + norm/relu + FC (mu/logvar) ----------------
__global__ __launch_bounds__(128) void k_fin(const float* __restrict__ part,
                                             const float* __restrict__ sums2,
                                             const float* __restrict__ Wmu, const float* __restrict__ bmu,
                                             const float* __restrict__ Wlv, const float* __restrict__ blv,
                                             float* __restrict__ out) {
    int b = blockIdx.x, tid = threadIdx.x;
    __shared__ float cb[256];
    const float M = (float)HID * (float)NODES;
#pragma unroll
    for (int enc = 0; enc < 2; ++enc) {
        int sb = enc * BATCH + b;
        float S = sums2[sb * 2], SS = sums2[sb * 2 + 1];
        float mean = S / M;
        float var = (SS - S * S / M) / (M - 1.f);
        float scale = 1.f / (sqrtf(fmaxf(var, 0.f)) + EPS);
        float m = 0.f;  // node-0 raw value is 0
#pragma unroll 4
        for (int s = 0; s < 32; ++s)
            m = fmaxf(m, part[((size_t)sb * 32 + s) * HID + tid]);
        float v = (m - mean) * scale;  // monotone: max then transform
        cb[enc * 128 + tid] = v > 0.f ? v : 0.f;
    }
    __syncthreads();
    const float* W = (tid < 64) ? Wmu : Wlv;
    int l = tid & 63;
    float s = (tid < 64) ? bmu[l] : blv[l];
    for (int j = 0; j < 256; ++j) s += cb[j] * W[l * 256 + j];
    out[(tid < 64 ? 0 : BATCH * 64) + b * 64 + l] = s;
}

extern "C" void kernel_launch(void* const* d_in, const int* in_sizes, int n_in,
                              void* d_out, int out_size, void* d_ws, size_t ws_size,
                              hipStream_t stream) {
    const int* children = (const int*)d_in[2];
    const float* Wmu = (const float*)d_in[11];
    const float* bmu = (const float*)d_in[12];
    const float* Wlv = (const float*)d_in[13];
    const float* blv = (const float*)d_in[14];

    // ---- workspace layout (256B aligned) ----
    char* ws = (char*)d_ws;
    size_t off = 0;
    auto alloc = [&](size_t bytes) { void* p = ws + off; off += (bytes + 255) & ~(size_t)255; return p; };
    float* sums = (float*)alloc(2 * 2 * BATCH * 2 * sizeof(float));  // [layer][enc*B+b][2]
    float* pool_part = (float*)alloc((size_t)2 * BATCH * 32 * HID * sizeof(float));
    __hip_bfloat16* Wp1 = (__hip_bfloat16*)alloc((size_t)2 * 3 * CIN * HID * sizeof(__hip_bfloat16));
    __hip_bfloat16* Wp2 = (__hip_bfloat16*)alloc((size_t)2 * 3 * HID * HID * sizeof(__hip_bfloat16));
    __hip_bfloat16* fT = (__hip_bfloat16*)alloc((size_t)2 * BATCH * NODES * CIN * sizeof(__hip_bfloat16));
    __hip_bfloat16* y1 = (__hip_bfloat16*)alloc((size_t)2 * BATCH * NODES * HID * sizeof(__hip_bfloat16));

    hipMemsetAsync(sums, 0, 2 * 2 * BATCH * 2 * sizeof(float), stream);

    k_wprep<<<dim3(3 * CIN * HID / 8 / 256, 2), 256, 0, stream>>>(
        (const float*)d_in[3], (const float*)d_in[7], Wp1, CIN);
    k_wprep<<<dim3(3 * HID * HID / 8 / 256, 2), 256, 0, stream>>>(
        (const float*)d_in[5], (const float*)d_in[9], Wp2, HID);
    k_transpose<<<dim3(129, 2, 2 * BATCH), dim3(32, 8), 0, stream>>>(
        (const float*)d_in[0], (const float*)d_in[1], fT);

    // layer 1: raw conv out -> y1, stats accumulated via per-wave atomics
    k_conv_mfma<CIN, false><<<4096, 256, 0, stream>>>(
        fT, children, Wp1, (const float*)d_in[4], (const float*)d_in[8],
        y1, sums, nullptr);
    // norm+relu y1 in place (stats computed inline from sums)
    k_norm<<<dim3((NODES * HID / 8 + 255) / 256, 2 * BATCH), 256, 0, stream>>>(y1, sums);
    // layer 2: plain gather of normalized y1
    k_conv_mfma<HID, true><<<4096, 256, 0, stream>>>(
        y1, children, Wp2, (const float*)d_in[6], (const float*)d_in[10],
        nullptr, sums + 256, pool_part);
    // stats2 + pool reduce + norm/relu + FC in one small kernel
    k_fin<<<BATCH, 128, 0, stream>>>(pool_part, sums + 256, Wmu, bmu, Wlv, blv, (float*)d_out);
}

// Round 8
// 522.599 us; speedup vs baseline: 1.0642x; 1.0060x over previous
//
#include <hip/hip_runtime.h>
#include <hip/hip_bf16.h>

#define NODES 4097
#define TT 4096
#define CIN 64
#define HID 128
#define BATCH 64
#define EPS 1e-5f

typedef short bf16x8 __attribute__((ext_vector_type(8)));   // 8 bf16 = 4 VGPRs
typedef float f32x16 __attribute__((ext_vector_type(16)));  // 32x32 acc

// async global->LDS DMA, 16 B per lane; LDS dst = wave-uniform base + lane*16
__device__ __forceinline__ void load_lds16(const void* g, void* l) {
    __builtin_amdgcn_global_load_lds(
        (const __attribute__((address_space(1))) unsigned int*)(uintptr_t)g,
        (__attribute__((address_space(3))) unsigned int*)(uintptr_t)l,
        16, 0, 0);
}

// ---------------- transpose feats (B,C,N) fp32 -> fT (B,N,C) bf16, both encoders ----------------
__global__ __launch_bounds__(256) void k_transpose(const float* __restrict__ f0,
                                                   const float* __restrict__ f1,
                                                   __hip_bfloat16* __restrict__ out) {
    __shared__ float tile[32][33];
    int z = blockIdx.z;
    int enc = z >> 6, b = z & 63;
    const float* in = enc ? f1 : f0;
    __hip_bfloat16* o = out + (size_t)enc * BATCH * NODES * CIN;
    int n0 = blockIdx.x * 32;
    int c0 = blockIdx.y * 32;
    int tx = threadIdx.x, ty = threadIdx.y;  // (32,8)
    for (int i = 0; i < 32; i += 8) {
        int n = n0 + tx, c = c0 + ty + i;
        float v = 0.f;
        if (n < NODES) v = in[((size_t)b * CIN + c) * NODES + n];
        tile[ty + i][tx] = v;
    }
    __syncthreads();
    for (int i = 0; i < 32; i += 8) {
        int n = n0 + ty + i, c = c0 + tx;
        if (n < NODES) o[((size_t)b * NODES + n) * CIN + c] = __float2bfloat16(tile[tx][ty + i]);
    }
}

// ---------------- W (HID,C,3) fp32 -> frag-major bf16 B-operand layout, both encoders ----------------
// Wp id = (ks*4 + ct)*64 + lane holds 8 bf16: B[k=ks*16+(lane>>5)*8+j][n=ct*32+(lane&31)]
// k = slot*C + c; B[k][n] = W[(n*C + c)*3 + slot]
__global__ void k_wprep(const float* __restrict__ W0, const float* __restrict__ W1,
                        __hip_bfloat16* __restrict__ Wp, int C) {
    int enc = blockIdx.y;
    const float* W = enc ? W1 : W0;
    __hip_bfloat16* o = Wp + (size_t)enc * 3 * C * HID;
    int id = blockIdx.x * 256 + threadIdx.x;
    int total = 3 * C * HID / 8;
    if (id >= total) return;
    int lane = id & 63;
    int ct = (id >> 6) & 3;
    int ks = id >> 8;
    int n = ct * 32 + (lane & 31);
    int kb = ks * 16 + (lane >> 5) * 8;
    union { int4 i; __hip_bfloat16 h[8]; } u;
#pragma unroll
    for (int j = 0; j < 8; ++j) {
        int k = kb + j;
        int slot = k / C, c = k % C;
        u.h[j] = __float2bfloat16(W[(n * C + c) * 3 + slot]);
    }
    ((int4*)o)[id] = u.i;
}

// ---------------- gather-conv via MFMA: B in LDS, A prefetched to registers ----------------
// Grid XCD-swizzled (xcd=L&7, node-tile-group fastest, b=xcd+8*bg pinned per XCD).
// Block = 4 waves; each tile = 128 nodes x 128 o; wave w covers nodes [+32w, +32).
// NT=1 (conv2): EXACT R0 structure -- per phase (PK=12) stage 48 KB Wp via
//   global_load_lds, prefetch the phase's 12 A-frags into regs before the
//   __syncthreads drain, then 48 MFMAs with zero global loads. PH=2 phases.
// NT=2 (conv1, PH==1): B fits LDS entirely, so ONE staging round + ONE drain is
//   amortized over 2 node-tiles. After the single __syncthreads, B_lds is
//   read-only and the epilogue uses no LDS -> ZERO further barriers. Tile t+1's
//   A-frags are refilled into areg[kk] right after tile t's MFMAs consume it
//   (live ranges disjoint -> no extra VGPR); their latency hides under t's
//   remaining MFMAs + 64-store epilogue.
// R0/R5/R7 lesson: wall time ~ linear in staging-round count (~30-40 us/round);
// counted-vmcnt pipelining recovers only ~1/3 of it -> cut rounds, not drains.
// R2 lesson: no __launch_bounds__ min-waves (acc spills). R1 lesson: keep
// >=3 blocks/CU and xt-fastest ordering (per-XCD gather set < 4 MB L2).
template <int C, bool POOL, int NT>
__global__ __launch_bounds__(256) void k_conv_mfma(
    const __hip_bfloat16* __restrict__ xT,    // [2][B][N][C]
    const int* __restrict__ children,
    const __hip_bfloat16* __restrict__ Wp,    // [2][3C*HID] frag-major
    const float* __restrict__ bias0, const float* __restrict__ bias1,
    __hip_bfloat16* __restrict__ y,           // [2][B][N][HID] raw out (if !POOL)
    float* __restrict__ sums,                 // [2B][2] this layer's sum/sumsq
    float* __restrict__ pool_part) {          // [2B][32][HID] (if POOL)
    constexpr int KSc = C / 16;             // ksteps per child-slot (4 or 8)
    constexpr int KS = 3 * KSc;             // 12 or 24 ksteps total
    constexpr int PK = 12;                  // ksteps per staging round (48 KB)
    constexpr int PH = KS / PK;             // 1 (conv1) or 2 (conv2)
    constexpr int XT = 32 / NT;             // node-tile groups per (enc,b)
    // ---- XCD-aware swizzle ----
    int L = blockIdx.x;
    int xcd = L & 7;
    int idx = L >> 3;
    int xt2 = idx % XT;             // tile-group (fastest within XCD)
    int bg = (idx / XT) & 7;
    int enc = idx / (XT * 8);
    int b = xcd + 8 * bg;           // b pinned to one XCD -> gather set stays in L2
    const int tid = threadIdx.x;
    const int lane = tid & 63;
    const int w = tid >> 6;
    const int hi = lane >> 5;

    __shared__ __align__(16) int4 B_lds[PK * 4 * 64];  // 48 KB, chunk c = (kk*4+cti)
    __shared__ float pm[8 * 128];                      // pool partial maxima (4 KB)

    const __hip_bfloat16* x = xT + (size_t)enc * BATCH * NODES * C;
    const int4* WpB = (const int4*)(Wp + (size_t)enc * 3 * C * HID);
    const float* bias = enc ? bias1 : bias0;
    const int sb = enc * BATCH + b;
    const size_t rowbase = (size_t)b * NODES;
    const long cb3 = (long)b * (3 * TT);
    const int nlane = w * 32 + (lane & 31);       // node offset within a tile

    float bsum = 0.f, bss = 0.f;
    __hip_bfloat16* yp = POOL ? nullptr : (y + (size_t)enc * BATCH * NODES * HID);

    if constexpr (NT == 1) {
        // ================= conv2 path: exact R0 =================
        const int t0 = xt2 * 128;
        const int tnode = t0 + nlane;
        const int4* ap[3];
#pragma unroll
        for (int s = 0; s < 3; ++s) {
            int child = children[cb3 + (long)tnode * 3 + s];
            ap[s] = (const int4*)(x + (rowbase + child) * C) + hi;
        }
        f32x16 acc[4] = {};
#pragma unroll
        for (int ph = 0; ph < PH; ++ph) {
            if (ph) __syncthreads();  // prior phase's ds_reads done before overwrite
#pragma unroll
            for (int i = 0; i < PK; ++i) {
                int c = w * PK + i;
                load_lds16(WpB + (size_t)(ph * PK * 4 + c) * 64 + lane, B_lds + c * 64);
            }
            int4 areg[PK];
#pragma unroll
            for (int kk = 0; kk < PK; ++kk) {
                int ksg = ph * PK + kk;
                areg[kk] = ap[ksg / KSc][(ksg % KSc) * 2];
            }
            __syncthreads();  // drains DMA + A-gathers + barrier
#pragma unroll
            for (int kk = 0; kk < PK; ++kk) {
                union { int4 i; bf16x8 v; } a;
                a.i = areg[kk];
#pragma unroll
                for (int cti = 0; cti < 4; ++cti) {
                    union { int4 i; bf16x8 v; } bb;
                    bb.i = B_lds[(kk * 4 + cti) * 64 + lane];
                    acc[cti] = __builtin_amdgcn_mfma_f32_32x32x16_bf16(a.v, bb.v, acc[cti], 0, 0, 0);
                }
            }
        }
        // epilogue (POOL)
        const int rbase = t0 + w * 32 + 4 * hi + 1;  // +1: node-0 shift
#pragma unroll
        for (int cti = 0; cti < 4; ++cti) {
            int o = cti * 32 + (lane & 31);
            float bv = bias[o];
            f32x16 a2 = acc[cti];
            float lmax = -3.4e38f;
#pragma unroll
            for (int reg = 0; reg < 16; ++reg) {
                float v = a2[reg] + bv;
                bsum += v;
                bss += v * v;
                lmax = fmaxf(lmax, v);
            }
            pm[(w * 2 + hi) * 128 + o] = lmax;  // o consecutive per lane: no conflicts
        }
        (void)rbase;
    } else {
        // ================= conv1 path: NT tiles share one staging round (PH==1) =================
        static_assert(PH == 1, "NT>1 requires fully-resident B");
        int ch[NT][3];
#pragma unroll
        for (int t = 0; t < NT; ++t) {
            int tn = (xt2 * NT + t) * 128 + nlane;
#pragma unroll
            for (int s = 0; s < 3; ++s) ch[t][s] = children[cb3 + (long)tn * 3 + s];
        }
        // stage ALL of B once
#pragma unroll
        for (int i = 0; i < PK; ++i) {
            int c = w * PK + i;
            load_lds16(WpB + (size_t)c * 64 + lane, B_lds + c * 64);
        }
        // gather tile 0
        int4 areg[KS];
#pragma unroll
        for (int kk = 0; kk < KS; ++kk)
            areg[kk] = ((const int4*)(x + (rowbase + ch[0][kk / KSc]) * C) + hi)[(kk % KSc) * 2];
        __syncthreads();  // the ONLY barrier: drains DMA + t0 gathers

#pragma unroll
        for (int t = 0; t < NT; ++t) {
            f32x16 acc[4] = {};
#pragma unroll
            for (int kk = 0; kk < KS; ++kk) {
                union { int4 i; bf16x8 v; } a;
                a.i = areg[kk];
#pragma unroll
                for (int cti = 0; cti < 4; ++cti) {
                    union { int4 i; bf16x8 v; } bb;
                    bb.i = B_lds[(kk * 4 + cti) * 64 + lane];
                    acc[cti] = __builtin_amdgcn_mfma_f32_32x32x16_bf16(a.v, bb.v, acc[cti], 0, 0, 0);
                }
                if (t + 1 < NT)  // refill right after last use: disjoint live range, latency hides
                    areg[kk] = ((const int4*)(x + (rowbase + ch[t + 1][kk / KSc]) * C) + hi)[(kk % KSc) * 2];
            }
            // epilogue tile t: bias + sums + y-write (no LDS, no barrier)
            const int rbase = (xt2 * NT + t) * 128 + w * 32 + 4 * hi + 1;  // +1: node-0 shift
#pragma unroll
            for (int cti = 0; cti < 4; ++cti) {
                int o = cti * 32 + (lane & 31);
                float bv = bias[o];
                f32x16 a2 = acc[cti];
#pragma unroll
                for (int reg = 0; reg < 16; ++reg) {
                    float v = a2[reg] + bv;
                    bsum += v;
                    bss += v * v;
                    int row = rbase + (reg & 3) + 8 * (reg >> 2);
                    yp[(rowbase + row) * HID + o] = __float2bfloat16(v);
                }
            }
        }
        if (xt2 == 0 && tid < HID)
            yp[rowbase * HID + tid] = __float2bfloat16(0.f);  // null-node column
    }

    // ---- wave-level sum/sumsq reduction: 6 shfl steps, no barriers ----
#pragma unroll
    for (int m2 = 1; m2 < 64; m2 <<= 1) {
        bsum += __shfl_xor(bsum, m2, 64);
        bss += __shfl_xor(bss, m2, 64);
    }
    if (lane == 0) {
        atomicAdd(&sums[sb * 2], bsum);
        atomicAdd(&sums[sb * 2 + 1], bss);
    }
    if (POOL) {
        __syncthreads();  // pm complete across waves
        if (tid < HID) {
            float m = -3.4e38f;
#pragma unroll
            for (int s2 = 0; s2 < 8; ++s2) m = fmaxf(m, pm[s2 * 128 + tid]);
            pool_part[((size_t)sb * 32 + xt2) * HID + tid] = m;
        }
    }
}

// ---------------- in-place norm+relu of y1 (bf16 x8 vectorized); stats from sums ----------------
__global__ __launch_bounds__(256) void k_norm(__hip_bfloat16* __restrict__ y,
                                              const float* __restrict__ sums) {
    constexpr int Q = NODES * HID / 8;  // 65552 int4s per (enc,b) slice
    int s = blockIdx.y;                 // enc*64 + b
    int q = blockIdx.x * 256 + threadIdx.x;
    if (q >= Q) return;
    const float M = (float)HID * (float)NODES;
    float S = sums[s * 2], SS = sums[s * 2 + 1];
    float mean = S / M;
    float var = (SS - S * S / M) / (M - 1.f);
    float scale = 1.f / (sqrtf(fmaxf(var, 0.f)) + EPS);
    int4* p = (int4*)(y + (size_t)s * NODES * HID) + q;
    union { int4 i; __hip_bfloat16 h[8]; } u;
    u.i = *p;
#pragma unroll
    for (int j = 0; j < 8; ++j) {
        float f = (__bfloat162float(u.h[j]) - mean) * scale;
        u.h[j] = __float2bfloat16(f > 0.f ? f : 0.f);
    }
    *p = u.i;
}

// ---------------- finalize: stats2 + pool reduce + norm/relu + FC (mu/logvar) ----------------
__global__ __launch_bounds__(128) void k_fin(const float* __restrict__ part,
                                             const float* __restrict__ sums2,
                                             const float* __restrict__ Wmu, const float* __restrict__ bmu,
                                             const float* __restrict__ Wlv, const float* __restrict__ blv,
                                             float* __restrict__ out) {
    int b = blockIdx.x, tid = threadIdx.x;
    __shared__ float cb[256];
    const float M = (float)HID * (float)NODES;
#pragma unroll
    for (int enc = 0; enc < 2; ++enc) {
        int sb = enc * BATCH + b;
        float S = sums2[sb * 2], SS = sums2[sb * 2 + 1];
        float mean = S / M;
        float var = (SS - S * S / M) / (M - 1.f);
        float scale = 1.f / (sqrtf(fmaxf(var, 0.f)) + EPS);
        float m = 0.f;  // node-0 raw value is 0
#pragma unroll 4
        for (int s = 0; s < 32; ++s)
            m = fmaxf(m, part[((size_t)sb * 32 + s) * HID + tid]);
        float v = (m - mean) * scale;  // monotone: max then transform
        cb[enc * 128 + tid] = v > 0.f ? v : 0.f;
    }
    __syncthreads();
    const float* W = (tid < 64) ? Wmu : Wlv;
    int l = tid & 63;
    float s = (tid < 64) ? bmu[l] : blv[l];
    for (int j = 0; j < 256; ++j) s += cb[j] * W[l * 256 + j];
    out[(tid < 64 ? 0 : BATCH * 64) + b * 64 + l] = s;
}

extern "C" void kernel_launch(void* const* d_in, const int* in_sizes, int n_in,
                              void* d_out, int out_size, void* d_ws, size_t ws_size,
                              hipStream_t stream) {
    const int* children = (const int*)d_in[2];
    const float* Wmu = (const float*)d_in[11];
    const float* bmu = (const float*)d_in[12];
    const float* Wlv = (const float*)d_in[13];
    const float* blv = (const float*)d_in[14];

    // ---- workspace layout (256B aligned) ----
    char* ws = (char*)d_ws;
    size_t off = 0;
    auto alloc = [&](size_t bytes) { void* p = ws + off; off += (bytes + 255) & ~(size_t)255; return p; };
    float* sums = (float*)alloc(2 * 2 * BATCH * 2 * sizeof(float));  // [layer][enc*B+b][2]
    float* pool_part = (float*)alloc((size_t)2 * BATCH * 32 * HID * sizeof(float));
    __hip_bfloat16* Wp1 = (__hip_bfloat16*)alloc((size_t)2 * 3 * CIN * HID * sizeof(__hip_bfloat16));
    __hip_bfloat16* Wp2 = (__hip_bfloat16*)alloc((size_t)2 * 3 * HID * HID * sizeof(__hip_bfloat16));
    __hip_bfloat16* fT = (__hip_bfloat16*)alloc((size_t)2 * BATCH * NODES * CIN * sizeof(__hip_bfloat16));
    __hip_bfloat16* y1 = (__hip_bfloat16*)alloc((size_t)2 * BATCH * NODES * HID * sizeof(__hip_bfloat16));

    hipMemsetAsync(sums, 0, 2 * 2 * BATCH * 2 * sizeof(float), stream);

    k_wprep<<<dim3(3 * CIN * HID / 8 / 256, 2), 256, 0, stream>>>(
        (const float*)d_in[3], (const float*)d_in[7], Wp1, CIN);
    k_wprep<<<dim3(3 * HID * HID / 8 / 256, 2), 256, 0, stream>>>(
        (const float*)d_in[5], (const float*)d_in[9], Wp2, HID);
    k_transpose<<<dim3(129, 2, 2 * BATCH), dim3(32, 8), 0, stream>>>(
        (const float*)d_in[0], (const float*)d_in[1], fT);

    // layer 1: NT=2 tiles per block (one staging round amortized), raw out + stats
    k_conv_mfma<CIN, false, 2><<<2048, 256, 0, stream>>>(
        fT, children, Wp1, (const float*)d_in[4], (const float*)d_in[8],
        y1, sums, nullptr);
    // norm+relu y1 in place (stats computed inline from sums)
    k_norm<<<dim3((NODES * HID / 8 + 255) / 256, 2 * BATCH), 256, 0, stream>>>(y1, sums);
    // layer 2: exact R0 structure (PK=12, PH=2, syncthreads)
    k_conv_mfma<HID, true, 1><<<4096, 256, 0, stream>>>(
        y1, children, Wp2, (const float*)d_in[6], (const float*)d_in[10],
        nullptr, sums + 256, pool_part);
    // stats2 + pool reduce + norm/relu + FC in one small kernel
    k_fin<<<BATCH, 128, 0, stream>>>(pool_part, sums + 256, Wmu, bmu, Wlv, blv, (float*)d_out);
}

// Round 9
// 406.954 us; speedup vs baseline: 1.3666x; 1.2842x over previous
//
#include <hip/hip_runtime.h>
#include <hip/hip_bf16.h>

#define NODES 4097
#define TT 4096
#define CIN 64
#define HID 128
#define BATCH 64
#define EPS 1e-5f
#define SSTR 16  // floats per (enc,b) sums slot: 64 B -> one cacheline per sb, XCD-local atomics

typedef short bf16x8 __attribute__((ext_vector_type(8)));   // 8 bf16 = 4 VGPRs
typedef float f32x16 __attribute__((ext_vector_type(16)));  // 32x32 acc

// async global->LDS DMA, 16 B per lane; LDS dst = wave-uniform base + lane*16
__device__ __forceinline__ void load_lds16(const void* g, void* l) {
    __builtin_amdgcn_global_load_lds(
        (const __attribute__((address_space(1))) unsigned int*)(uintptr_t)g,
        (__attribute__((address_space(3))) unsigned int*)(uintptr_t)l,
        16, 0, 0);
}

// ---------------- transpose feats (B,C,N) fp32 -> fT (B,N,C) bf16, both encoders ----------------
__global__ __launch_bounds__(256) void k_transpose(const float* __restrict__ f0,
                                                   const float* __restrict__ f1,
                                                   __hip_bfloat16* __restrict__ out) {
    __shared__ float tile[32][33];
    int z = blockIdx.z;
    int enc = z >> 6, b = z & 63;
    const float* in = enc ? f1 : f0;
    __hip_bfloat16* o = out + (size_t)enc * BATCH * NODES * CIN;
    int n0 = blockIdx.x * 32;
    int c0 = blockIdx.y * 32;
    int tx = threadIdx.x, ty = threadIdx.y;  // (32,8)
    for (int i = 0; i < 32; i += 8) {
        int n = n0 + tx, c = c0 + ty + i;
        float v = 0.f;
        if (n < NODES) v = in[((size_t)b * CIN + c) * NODES + n];
        tile[ty + i][tx] = v;
    }
    __syncthreads();
    for (int i = 0; i < 32; i += 8) {
        int n = n0 + ty + i, c = c0 + tx;
        if (n < NODES) o[((size_t)b * NODES + n) * CIN + c] = __float2bfloat16(tile[tx][ty + i]);
    }
}

// ---------------- W (HID,C,3) fp32 -> frag-major bf16 B-operand layout, both encoders ----------------
// Wp id = (ks*4 + ct)*64 + lane holds 8 bf16: B[k=ks*16+(lane>>5)*8+j][n=ct*32+(lane&31)]
// k = slot*C + c; B[k][n] = W[(n*C + c)*3 + slot]
__global__ void k_wprep(const float* __restrict__ W0, const float* __restrict__ W1,
                        __hip_bfloat16* __restrict__ Wp, int C) {
    int enc = blockIdx.y;
    const float* W = enc ? W1 : W0;
    __hip_bfloat16* o = Wp + (size_t)enc * 3 * C * HID;
    int id = blockIdx.x * 256 + threadIdx.x;
    int total = 3 * C * HID / 8;
    if (id >= total) return;
    int lane = id & 63;
    int ct = (id >> 6) & 3;
    int ks = id >> 8;
    int n = ct * 32 + (lane & 31);
    int kb = ks * 16 + (lane >> 5) * 8;
    union { int4 i; __hip_bfloat16 h[8]; } u;
#pragma unroll
    for (int j = 0; j < 8; ++j) {
        int k = kb + j;
        int slot = k / C, c = k % C;
        u.h[j] = __float2bfloat16(W[(n * C + c) * 3 + slot]);
    }
    ((int4*)o)[id] = u.i;
}

// ---------------- gather-conv via MFMA: B in LDS, A prefetched to registers ----------------
// Grid XCD-swizzled (xcd=L&7, node-tile-group fastest, b=xcd+8*bg pinned per XCD).
// Block = 4 waves; each tile = 128 nodes x 128 o; wave w covers nodes [+32w, +32).
// NT=1 (conv2): R0 structure -- per phase (PK=12) stage 48 KB Wp via global_load_lds,
//   prefetch the phase's 12 A-frags into regs before the __syncthreads drain, then
//   48 MFMAs with zero global loads. PH=2 phases.
// NT=2 (conv1, PH==1): B fully resident -> ONE staging round amortized over 2 tiles;
//   after the single drain, zero further barriers until the tail. Tile t+1's A-frags
//   refill areg[kk] right after tile t consumes it (disjoint live ranges).
// TAIL (R8 lesson): BOTH convs regressed identically (93->157) when the tail used
//   per-wave atomics on 8B-packed sums -- consecutive sb = consecutive XCD, so every
//   64B line was an 8-XCD-contended atomic RMW target. Fix: sums padded to 64 B per
//   sb (line owned by ONE XCD since b is XCD-pinned) + ONE atomic pair per block
//   (wave shfl -> 8 LDS floats -> barrier -> tid0 adds + single atomicAdd pair).
// R2 lesson: no __launch_bounds__ min-waves (acc spills). R1 lesson: keep >=3
// blocks/CU and tile-fastest ordering (per-XCD gather set < 4 MB L2).
template <int C, bool POOL, int NT>
__global__ __launch_bounds__(256) void k_conv_mfma(
    const __hip_bfloat16* __restrict__ xT,    // [2][B][N][C]
    const int* __restrict__ children,
    const __hip_bfloat16* __restrict__ Wp,    // [2][3C*HID] frag-major
    const float* __restrict__ bias0, const float* __restrict__ bias1,
    __hip_bfloat16* __restrict__ y,           // [2][B][N][HID] raw out (if !POOL)
    float* __restrict__ sums,                 // [2B][SSTR] this layer's sum/sumsq
    float* __restrict__ pool_part) {          // [2B][32][HID] (if POOL)
    constexpr int KSc = C / 16;             // ksteps per child-slot (4 or 8)
    constexpr int KS = 3 * KSc;             // 12 or 24 ksteps total
    constexpr int PK = 12;                  // ksteps per staging round (48 KB)
    constexpr int PH = KS / PK;             // 1 (conv1) or 2 (conv2)
    constexpr int XT = 32 / NT;             // node-tile groups per (enc,b)
    // ---- XCD-aware swizzle ----
    int L = blockIdx.x;
    int xcd = L & 7;
    int idx = L >> 3;
    int xt2 = idx % XT;             // tile-group (fastest within XCD)
    int bg = (idx / XT) & 7;
    int enc = idx / (XT * 8);
    int b = xcd + 8 * bg;           // b pinned to one XCD -> gather set stays in L2
    const int tid = threadIdx.x;
    const int lane = tid & 63;
    const int w = tid >> 6;
    const int hi = lane >> 5;

    __shared__ __align__(16) int4 B_lds[PK * 4 * 64];   // 48 KB, chunk c = (kk*4+cti)
    __shared__ float pm[POOL ? 8 * 128 : 8];            // pool partial maxima (POOL only)
    __shared__ float wred[8];                           // 4 waves x {sum, sumsq}

    const __hip_bfloat16* x = xT + (size_t)enc * BATCH * NODES * C;
    const int4* WpB = (const int4*)(Wp + (size_t)enc * 3 * C * HID);
    const float* bias = enc ? bias1 : bias0;
    const int sb = enc * BATCH + b;
    const size_t rowbase = (size_t)b * NODES;
    const long cb3 = (long)b * (3 * TT);
    const int nlane = w * 32 + (lane & 31);       // node offset within a tile

    float bsum = 0.f, bss = 0.f;
    __hip_bfloat16* yp = POOL ? nullptr : (y + (size_t)enc * BATCH * NODES * HID);

    if constexpr (NT == 1) {
        // ================= conv2 path: R0 structure =================
        const int t0 = xt2 * 128;
        const int tnode = t0 + nlane;
        const int4* ap[3];
#pragma unroll
        for (int s = 0; s < 3; ++s) {
            int child = children[cb3 + (long)tnode * 3 + s];
            ap[s] = (const int4*)(x + (rowbase + child) * C) + hi;
        }
        f32x16 acc[4] = {};
#pragma unroll
        for (int ph = 0; ph < PH; ++ph) {
            if (ph) __syncthreads();  // prior phase's ds_reads done before overwrite
#pragma unroll
            for (int i = 0; i < PK; ++i) {
                int c = w * PK + i;
                load_lds16(WpB + (size_t)(ph * PK * 4 + c) * 64 + lane, B_lds + c * 64);
            }
            int4 areg[PK];
#pragma unroll
            for (int kk = 0; kk < PK; ++kk) {
                int ksg = ph * PK + kk;
                areg[kk] = ap[ksg / KSc][(ksg % KSc) * 2];
            }
            __syncthreads();  // drains DMA + A-gathers + barrier
#pragma unroll
            for (int kk = 0; kk < PK; ++kk) {
                union { int4 i; bf16x8 v; } a;
                a.i = areg[kk];
#pragma unroll
                for (int cti = 0; cti < 4; ++cti) {
                    union { int4 i; bf16x8 v; } bb;
                    bb.i = B_lds[(kk * 4 + cti) * 64 + lane];
                    acc[cti] = __builtin_amdgcn_mfma_f32_32x32x16_bf16(a.v, bb.v, acc[cti], 0, 0, 0);
                }
            }
        }
        // epilogue (POOL)
#pragma unroll
        for (int cti = 0; cti < 4; ++cti) {
            int o = cti * 32 + (lane & 31);
            float bv = bias[o];
            f32x16 a2 = acc[cti];
            float lmax = -3.4e38f;
#pragma unroll
            for (int reg = 0; reg < 16; ++reg) {
                float v = a2[reg] + bv;
                bsum += v;
                bss += v * v;
                lmax = fmaxf(lmax, v);
            }
            pm[(w * 2 + hi) * 128 + o] = lmax;  // o consecutive per lane: no conflicts
        }
    } else {
        // ================= conv1 path: NT tiles share one staging round (PH==1) =================
        static_assert(PH == 1, "NT>1 requires fully-resident B");
        int ch[NT][3];
#pragma unroll
        for (int t = 0; t < NT; ++t) {
            int tn = (xt2 * NT + t) * 128 + nlane;
#pragma unroll
            for (int s = 0; s < 3; ++s) ch[t][s] = children[cb3 + (long)tn * 3 + s];
        }
        // stage ALL of B once
#pragma unroll
        for (int i = 0; i < PK; ++i) {
            int c = w * PK + i;
            load_lds16(WpB + (size_t)c * 64 + lane, B_lds + c * 64);
        }
        // gather tile 0
        int4 areg[KS];
#pragma unroll
        for (int kk = 0; kk < KS; ++kk)
            areg[kk] = ((const int4*)(x + (rowbase + ch[0][kk / KSc]) * C) + hi)[(kk % KSc) * 2];
        __syncthreads();  // the ONLY staging barrier: drains DMA + t0 gathers

#pragma unroll
        for (int t = 0; t < NT; ++t) {
            f32x16 acc[4] = {};
#pragma unroll
            for (int kk = 0; kk < KS; ++kk) {
                union { int4 i; bf16x8 v; } a;
                a.i = areg[kk];
#pragma unroll
                for (int cti = 0; cti < 4; ++cti) {
                    union { int4 i; bf16x8 v; } bb;
                    bb.i = B_lds[(kk * 4 + cti) * 64 + lane];
                    acc[cti] = __builtin_amdgcn_mfma_f32_32x32x16_bf16(a.v, bb.v, acc[cti], 0, 0, 0);
                }
                if (t + 1 < NT)  // refill right after last use: disjoint live range, latency hides
                    areg[kk] = ((const int4*)(x + (rowbase + ch[t + 1][kk / KSc]) * C) + hi)[(kk % KSc) * 2];
            }
            // epilogue tile t: bias + sums + y-write (no LDS, no barrier)
            const int rbase = (xt2 * NT + t) * 128 + w * 32 + 4 * hi + 1;  // +1: node-0 shift
#pragma unroll
            for (int cti = 0; cti < 4; ++cti) {
                int o = cti * 32 + (lane & 31);
                float bv = bias[o];
                f32x16 a2 = acc[cti];
#pragma unroll
                for (int reg = 0; reg < 16; ++reg) {
                    float v = a2[reg] + bv;
                    bsum += v;
                    bss += v * v;
                    int row = rbase + (reg & 3) + 8 * (reg >> 2);
                    yp[(rowbase + row) * HID + o] = __float2bfloat16(v);
                }
            }
        }
        if (xt2 == 0 && tid < HID)
            yp[rowbase * HID + tid] = __float2bfloat16(0.f);  // null-node column
    }

    // ---- tail: wave shfl-reduce (no barriers) -> 8 LDS floats -> ONE atomic pair/block ----
#pragma unroll
    for (int m2 = 1; m2 < 64; m2 <<= 1) {
        bsum += __shfl_xor(bsum, m2, 64);
        bss += __shfl_xor(bss, m2, 64);
    }
    if (lane == 0) { wred[w * 2] = bsum; wred[w * 2 + 1] = bss; }
    __syncthreads();  // wred (and pm, if POOL) complete across waves
    if (tid == 0) {
        atomicAdd(&sums[sb * SSTR], wred[0] + wred[2] + wred[4] + wred[6]);
        atomicAdd(&sums[sb * SSTR + 1], wred[1] + wred[3] + wred[5] + wred[7]);
    }
    if (POOL && tid < HID) {
        float m = -3.4e38f;
#pragma unroll
        for (int s2 = 0; s2 < 8; ++s2) m = fmaxf(m, pm[s2 * 128 + tid]);
        pool_part[((size_t)sb * 32 + xt2) * HID + tid] = m;
    }
}

// ---------------- in-place norm+relu of y1 (bf16 x8 vectorized); stats from sums ----------------
__global__ __launch_bounds__(256) void k_norm(__hip_bfloat16* __restrict__ y,
                                              const float* __restrict__ sums) {
    constexpr int Q = NODES * HID / 8;  // 65552 int4s per (enc,b) slice
    int s = blockIdx.y;                 // enc*64 + b
    int q = blockIdx.x * 256 + threadIdx.x;
    if (q >= Q) return;
    const float M = (float)HID * (float)NODES;
    float S = sums[s * SSTR], SS = sums[s * SSTR + 1];
    float mean = S / M;
    float var = (SS - S * S / M) / (M - 1.f);
    float scale = 1.f / (sqrtf(fmaxf(var, 0.f)) + EPS);
    int4* p = (int4*)(y + (size_t)s * NODES * HID) + q;
    union { int4 i; __hip_bfloat16 h[8]; } u;
    u.i = *p;
#pragma unroll
    for (int j = 0; j < 8; ++j) {
        float f = (__bfloat162float(u.h[j]) - mean) * scale;
        u.h[j] = __float2bfloat16(f > 0.f ? f : 0.f);
    }
    *p = u.i;
}

// ---------------- finalize: stats2 + pool reduce + norm/relu + FC (mu/logvar) ----------------
__global__ __launch_bounds__(128) void k_fin(const float* __restrict__ part,
                                             const float* __restrict__ sums2,
                                             const float* __restrict__ Wmu, const float* __restrict__ bmu,
                                             const float* __restrict__ Wlv, const float* __restrict__ blv,
                                             float* __restrict__ out) {
    int b = blockIdx.x, tid = threadIdx.x;
    __shared__ float cb[256];
    const float M = (float)HID * (float)NODES;
#pragma unroll
    for (int enc = 0; enc < 2; ++enc) {
        int sb = enc * BATCH + b;
        float S = sums2[sb * SSTR], SS = sums2[sb * SSTR + 1];
        float mean = S / M;
        float var = (SS - S * S / M) / (M - 1.f);
        float scale = 1.f / (sqrtf(fmaxf(var, 0.f)) + EPS);
        float m = 0.f;  // node-0 raw value is 0
#pragma unroll 4
        for (int s = 0; s < 32; ++s)
            m = fmaxf(m, part[((size_t)sb * 32 + s) * HID + tid]);
        float v = (m - mean) * scale;  // monotone: max then transform
        cb[enc * 128 + tid] = v > 0.f ? v : 0.f;
    }
    __syncthreads();
    const float* W = (tid < 64) ? Wmu : Wlv;
    int l = tid & 63;
    float s = (tid < 64) ? bmu[l] : blv[l];
    for (int j = 0; j < 256; ++j) s += cb[j] * W[l * 256 + j];
    out[(tid < 64 ? 0 : BATCH * 64) + b * 64 + l] = s;
}

extern "C" void kernel_launch(void* const* d_in, const int* in_sizes, int n_in,
                              void* d_out, int out_size, void* d_ws, size_t ws_size,
                              hipStream_t stream) {
    const int* children = (const int*)d_in[2];
    const float* Wmu = (const float*)d_in[11];
    const float* bmu = (const float*)d_in[12];
    const float* Wlv = (const float*)d_in[13];
    const float* blv = (const float*)d_in[14];

    // ---- workspace layout (256B aligned) ----
    char* ws = (char*)d_ws;
    size_t off = 0;
    auto alloc = [&](size_t bytes) { void* p = ws + off; off += (bytes + 255) & ~(size_t)255; return p; };
    float* sums = (float*)alloc(2 * 2 * BATCH * SSTR * sizeof(float));  // [layer][sb][SSTR]
    float* pool_part = (float*)alloc((size_t)2 * BATCH * 32 * HID * sizeof(float));
    __hip_bfloat16* Wp1 = (__hip_bfloat16*)alloc((size_t)2 * 3 * CIN * HID * sizeof(__hip_bfloat16));
    __hip_bfloat16* Wp2 = (__hip_bfloat16*)alloc((size_t)2 * 3 * HID * HID * sizeof(__hip_bfloat16));
    __hip_bfloat16* fT = (__hip_bfloat16*)alloc((size_t)2 * BATCH * NODES * CIN * sizeof(__hip_bfloat16));
    __hip_bfloat16* y1 = (__hip_bfloat16*)alloc((size_t)2 * BATCH * NODES * HID * sizeof(__hip_bfloat16));

    hipMemsetAsync(sums, 0, 2 * 2 * BATCH * SSTR * sizeof(float), stream);

    k_wprep<<<dim3(3 * CIN * HID / 8 / 256, 2), 256, 0, stream>>>(
        (const float*)d_in[3], (const float*)d_in[7], Wp1, CIN);
    k_wprep<<<dim3(3 * HID * HID / 8 / 256, 2), 256, 0, stream>>>(
        (const float*)d_in[5], (const float*)d_in[9], Wp2, HID);
    k_transpose<<<dim3(129, 2, 2 * BATCH), dim3(32, 8), 0, stream>>>(
        (const float*)d_in[0], (const float*)d_in[1], fT);

    // layer 1: NT=2 tiles per block (one staging round amortized), raw out + stats
    k_conv_mfma<CIN, false, 2><<<2048, 256, 0, stream>>>(
        fT, children, Wp1, (const float*)d_in[4], (const float*)d_in[8],
        y1, sums, nullptr);
    // norm+relu y1 in place (stats computed inline from sums)
    k_norm<<<dim3((NODES * HID / 8 + 255) / 256, 2 * BATCH), 256, 0, stream>>>(y1, sums);
    // layer 2: R0 structure (PK=12, PH=2, syncthreads)
    k_conv_mfma<HID, true, 1><<<4096, 256, 0, stream>>>(
        y1, children, Wp2, (const float*)d_in[6], (const float*)d_in[10],
        nullptr, sums + 2 * BATCH * SSTR, pool_part);
    // stats2 + pool reduce + norm/relu + FC in one small kernel
    k_fin<<<BATCH, 128, 0, stream>>>(pool_part, sums + 2 * BATCH * SSTR, Wmu, bmu, Wlv, blv, (float*)d_out);
}